// Round 5
// baseline (1636.214 us; speedup 1.0000x reference)
//
#include <hip/hip_runtime.h>

// LSTM: SEQ=512, B=64, IN=256, H=512, fp32 in/out; bf16 MFMA compute.
// Round-0 proven topology: 4 batch-groups x 16 H-slice blocks (32 hid x 4
// gates), persistent, 512 steps, M=16 full MFMA.
//
// Exchange protocol (v5, single round trip):
//  - payload: self-certifying 16B packets [4 x bf16 | tag=t+1 | tag], single
//    global_store_dwordx4 sc0 sc1 => tag travels WITH data. No ack, no flag,
//    no producer vmcnt drain. 2-slot buffer by (t&1).
//  - certification: tid2 (a thread with ZERO outstanding VMEM => its
//    vmcnt(0) waits only its own poll loads) polls 16 sentinel packets
//    (one per producer: that producer's first packet tag). Low contention:
//    16 dword pollers per group, not 32K wide spinners (round-1's mistake).
//  - then barrier; all threads bulk-load their 4 packets ONCE and verify
//    embedded tags (retry only for stragglers the sentinel missed - rare).
//  - slot reuse safe: producer writes slot p for step t+2 only after its
//    step-t+1 sentinel poll saw all peers at t+2, which each peer publishes
//    only after its step-t reads of slot p completed (program order).
//  - x(t+2) prefetch + h_seq out store issued AFTER the poll, inside the
//    bulk-load RT shadow => no vmcnt(0) anywhere waits on HBM/store-acks.
// Barriers: 3/step, LDS-only or raw (no implicit vmcnt(0) drains).
// g_lds stride 320: gate-output writes are 2-way bank aliases (free) not 4-way.

#define T_STEPS 512
#define BATCH   64
#define IN_D    256
#define HID     512
#define NGROUP  4
#define NSLICE  16
#define BLK_B   16
#define BLK_H   32
#define THREADS 512
#define CH_ROW  128                            // 16B packets per row: 512 hid / 4
#define SLOT_BYTES (BATCH * CH_ROW * 16)       // 131072 (256 KB total, as round-1)

using short8  = __attribute__((ext_vector_type(8))) short;
using int4v   = __attribute__((ext_vector_type(4))) int;
using float4v = __attribute__((ext_vector_type(4))) float;

#define FRAG_ADDR(f) (((f) << 4) + (((f) >> 4) << 4))   // 16B frag + 16B pad / 16 frags

__device__ __forceinline__ unsigned short f2bf(float f) {
    union { float f; unsigned int i; } v; v.f = f;
    unsigned int r = v.i + 0x7fff + ((v.i >> 16) & 1);
    return (unsigned short)(r >> 16);
}
__device__ __forceinline__ short8 pack8(float4 a, float4 b) {
    short8 s;
    s[0]=(short)f2bf(a.x); s[1]=(short)f2bf(a.y); s[2]=(short)f2bf(a.z); s[3]=(short)f2bf(a.w);
    s[4]=(short)f2bf(b.x); s[5]=(short)f2bf(b.y); s[6]=(short)f2bf(b.z); s[7]=(short)f2bf(b.w);
    return s;
}
__device__ __forceinline__ float sigm(float v) { return 1.0f / (1.0f + __expf(-v)); }
__device__ __forceinline__ float tanh_(float v) { return 2.0f / (1.0f + __expf(-2.0f * v)) - 1.0f; }

// LDS-visibility barrier WITHOUT the vmcnt(0) drain of __syncthreads.
__device__ __forceinline__ void lds_barrier() {
    asm volatile("s_waitcnt lgkmcnt(0)" ::: "memory");
    __builtin_amdgcn_s_barrier();
    __builtin_amdgcn_sched_barrier(0);
}

__global__ __launch_bounds__(256, 1) void lstm_init_ws(unsigned int* w, int n) {
    int i = blockIdx.x * blockDim.x + threadIdx.x;
    if (i < n) __hip_atomic_store(&w[i], 0u, __ATOMIC_RELAXED, __HIP_MEMORY_SCOPE_AGENT);
}

__global__ __launch_bounds__(THREADS, 1) void lstm_persist(
    const float* __restrict__ x,
    const float* __restrict__ h0,
    const float* __restrict__ c0,
    const float* __restrict__ Wf, const float* __restrict__ Wfb,
    const float* __restrict__ Uf, const float* __restrict__ Ufb,
    const float* __restrict__ Wi, const float* __restrict__ Wib,
    const float* __restrict__ Ui, const float* __restrict__ Uib,
    const float* __restrict__ Wo, const float* __restrict__ Wob,
    const float* __restrict__ Uo, const float* __restrict__ Uob,
    const float* __restrict__ Wc, const float* __restrict__ Wcb,
    const float* __restrict__ Uc, const float* __restrict__ Ucb,
    float* out,                  // h_seq (T,B,H) | h (B,H) | c (B,H), fp32
    unsigned char* exch)         // [2 slots][64 rows][128 packets][16B]
{
    __shared__ __attribute__((aligned(16))) unsigned char hfrag[17392]; // 1024 frags
    __shared__ __attribute__((aligned(16))) unsigned char xfrag[8688];  // 512 frags
    __shared__ float g_lds[8 * 320];   // gate outputs, 2-way-max banks

    const int tid  = threadIdx.x;
    const int lane = tid & 63;
    const int wave = tid >> 6;            // 0..7
    const int gate = wave >> 1;           // 0:f 1:i 2:o 3:c
    const int hlf  = wave & 1;            // 16-hid half of the 32
    const int grp  = blockIdx.x & 3;      // batch group
    const int slc  = blockIdx.x >> 2;     // hid slice
    const int bb   = grp * BLK_B;
    const int hbase= slc * BLK_H;
    const int lm   = lane & 15;
    const int lq   = lane >> 4;
    const int row  = tid >> 5;            // 0..15 (batch within group)
    const int seg  = tid & 31;            // 0..31

    const float* Ug  = (gate == 0) ? Uf : (gate == 1) ? Ui : (gate == 2) ? Uo : Uc;
    const float* Wg  = (gate == 0) ? Wf : (gate == 1) ? Wi : (gate == 2) ? Wo : Wc;
    const float* Wbg = (gate == 0) ? Wfb : (gate == 1) ? Wib : (gate == 2) ? Wob : Wcb;
    const float* Ubg = (gate == 0) ? Ufb : (gate == 1) ? Uib : (gate == 2) ? Uob : Ucb;
    const int ng = hbase + hlf * 16 + lm;   // lane's gate-output row (B-op n)

    // ---- register-resident bf16 weight fragments ----
    short8 ufrag[16];
#pragma unroll
    for (int ks = 0; ks < 16; ++ks) {
        const float* p = Ug + (size_t)ng * HID + ks * 32 + lq * 8;
        ufrag[ks] = pack8(*(const float4*)(p), *(const float4*)(p + 4));
    }
    short8 wfrag[8];
#pragma unroll
    for (int ks = 0; ks < 8; ++ks) {
        const float* p = Wg + (size_t)ng * IN_D + ks * 32 + lq * 8;
        wfrag[ks] = pack8(*(const float4*)(p), *(const float4*)(p + 4));
    }
    const float bias = Wbg[ng] + Ubg[ng];

    // ---- cell state in registers: thread (row,seg) owns c[row][hbase+seg] ----
    float c_reg = c0[(size_t)(bb + row) * HID + hbase + seg];

    // ---- stage h0 (2 frags/thread) and x0 (1 frag/thread) ----
    {
        const float* ph = h0 + (size_t)(bb + row) * HID + seg * 16;
        int f0 = (seg >> 1) * 64 + (seg & 1) * 32 + row;
        *(short8*)(hfrag + FRAG_ADDR(f0))      = pack8(*(const float4*)(ph),     *(const float4*)(ph + 4));
        *(short8*)(hfrag + FRAG_ADDR(f0 + 16)) = pack8(*(const float4*)(ph + 8), *(const float4*)(ph + 12));

        const float* px = x + (size_t)(bb + row) * IN_D + seg * 8;
        int fx = (seg >> 2) * 64 + (seg & 3) * 16 + row;
        *(short8*)(xfrag + FRAG_ADDR(fx)) = pack8(*(const float4*)(px), *(const float4*)(px + 4));
    }
    // preload x(1) into parity pair A
    float4 xa0, xa1, xb0 = {0,0,0,0}, xb1 = {0,0,0,0};
    {
        const float* px = x + ((size_t)1 * BATCH + bb + row) * IN_D + seg * 8;
        xa0 = *(const float4*)(px); xa1 = *(const float4*)(px + 4);
    }
    __syncthreads();

    // accx = bias + x_0 @ W^T
    float4v accx0 = {bias, bias, bias, bias};
    float4v accx1 = {0.f, 0.f, 0.f, 0.f};
#pragma unroll
    for (int ks = 0; ks < 8; ++ks) {
        short8 a = *(const short8*)(xfrag + FRAG_ADDR(ks * 64 + lane));
        if (ks & 1) accx1 = __builtin_amdgcn_mfma_f32_16x16x32_bf16(a, wfrag[ks], accx1, 0, 0, 0);
        else        accx0 = __builtin_amdgcn_mfma_f32_16x16x32_bf16(a, wfrag[ks], accx0, 0, 0, 0);
    }

    float* const out_h = out + (size_t)T_STEPS * BATCH * HID;
    float* const out_c = out_h + (size_t)BATCH * HID;

    // exchange addresses (packet = 16B covering 4 hid)
    unsigned char* const ex_wr = exch
        + (size_t)((bb + row) * CH_ROW + slc * 8 + (seg >> 2)) * 16;
    const unsigned char* const ex_rd = exch
        + (size_t)((bb + row) * CH_ROW + seg * 4) * 16;
    // sentinel tags: producer i's first packet (row bb+0, packet i*8), word[2]
    const unsigned char* const snt = exch + (size_t)bb * CH_ROW * 16 + 8;

    auto STEP = [&](int t, float4& sx0, float4& sx1, float4& px0, float4& px1) {
        // ---- 1. h-part MFMAs on top of accx ----
        float4v acc0 = accx0, acc1 = accx1;
#pragma unroll
        for (int ks = 0; ks < 16; ++ks) {
            short8 a = *(const short8*)(hfrag + FRAG_ADDR(ks * 64 + lane));
            if (ks & 1) acc1 = __builtin_amdgcn_mfma_f32_16x16x32_bf16(a, ufrag[ks], acc1, 0, 0, 0);
            else        acc0 = __builtin_amdgcn_mfma_f32_16x16x32_bf16(a, ufrag[ks], acc0, 0, 0, 0);
        }
        float4v acc = acc0 + acc1;
#pragma unroll
        for (int r = 0; r < 4; ++r)
            g_lds[wave * 320 + lq * 80 + r * 16 + lm] = acc[r];

        // ---- stage xfrag(t+1) from parity regs (loaded LAST iteration) ----
        if (t + 1 < T_STEPS) {
            int fx = (seg >> 2) * 64 + (seg & 3) * 16 + row;
            *(short8*)(xfrag + FRAG_ADDR(fx)) = pack8(sx0, sx1);
        }

        lds_barrier();   // A: g_lds + xfrag visible; hfrag MFMA reads drained

        // ---- 3. pointwise (fp32, c in register) ----
        float hv;
        {
            int hf2 = seg >> 4, nn = seg & 15;
            int rbase = (row >> 2) * 80 + (row & 3) * 16 + nn;
            float fpre = g_lds[(0 * 2 + hf2) * 320 + rbase];
            float ipre = g_lds[(1 * 2 + hf2) * 320 + rbase];
            float opre = g_lds[(2 * 2 + hf2) * 320 + rbase];
            float gpre = g_lds[(3 * 2 + hf2) * 320 + rbase];
            float fv = sigm(fpre), iv = sigm(ipre), ov = sigm(opre);
            float gv = tanh_(gpre);
            c_reg = fv * c_reg + iv * gv;
            hv = ov * tanh_(c_reg);
        }

        if (t + 1 < T_STEPS) {
            const size_t so = (size_t)(t & 1) * SLOT_BYTES;
            const unsigned int want = (unsigned int)(t + 1);

            // ---- 4. publish self-certifying packets (no ack, no flag) ----
            {
                unsigned int bfv = f2bf(hv);
                unsigned int nb  = (unsigned int)__shfl_xor((int)bfv, 1);
                unsigned int p   = bfv | (nb << 16);          // even lanes: 2 bf16
                unsigned int q   = (unsigned int)__shfl_xor((int)p, 2);
                if ((tid & 3) == 0) {
                    int4v ch; ch[0] = (int)p; ch[1] = (int)q;
                    ch[2] = (int)want; ch[3] = (int)want;
                    asm volatile("global_store_dwordx4 %0, %1, off sc0 sc1"
                                 :: "v"(ex_wr + so), "v"(ch) : "memory");
                }
            }

            // ---- 7. accx for t+1 (overlaps packet flight) ----
            accx0 = (float4v){bias, bias, bias, bias};
            accx1 = (float4v){0.f, 0.f, 0.f, 0.f};
#pragma unroll
            for (int ks = 0; ks < 8; ++ks) {
                short8 a = *(const short8*)(xfrag + FRAG_ADDR(ks * 64 + lane));
                if (ks & 1) accx1 = __builtin_amdgcn_mfma_f32_16x16x32_bf16(a, wfrag[ks], accx1, 0, 0, 0);
                else        accx0 = __builtin_amdgcn_mfma_f32_16x16x32_bf16(a, wfrag[ks], accx0, 0, 0, 0);
            }

            // ---- 8. tid2 polls 16 sentinel tags (clean vmcnt: no own VMEM) ----
            if (tid == 2) {
                const unsigned char* sb = snt + so;
                unsigned int v0,v1,v2,v3,v4,v5,v6,v7,v8,v9,v10,v11,v12,v13,v14,v15;
                long guard = 0;
                for (;;) {
                    asm volatile(
                        "global_load_dword %0,  %16, off sc0 sc1\n\t"
                        "global_load_dword %1,  %16, off offset:128 sc0 sc1\n\t"
                        "global_load_dword %2,  %16, off offset:256 sc0 sc1\n\t"
                        "global_load_dword %3,  %16, off offset:384 sc0 sc1\n\t"
                        "global_load_dword %4,  %16, off offset:512 sc0 sc1\n\t"
                        "global_load_dword %5,  %16, off offset:640 sc0 sc1\n\t"
                        "global_load_dword %6,  %16, off offset:768 sc0 sc1\n\t"
                        "global_load_dword %7,  %16, off offset:896 sc0 sc1\n\t"
                        "global_load_dword %8,  %16, off offset:1024 sc0 sc1\n\t"
                        "global_load_dword %9,  %16, off offset:1152 sc0 sc1\n\t"
                        "global_load_dword %10, %16, off offset:1280 sc0 sc1\n\t"
                        "global_load_dword %11, %16, off offset:1408 sc0 sc1\n\t"
                        "global_load_dword %12, %16, off offset:1536 sc0 sc1\n\t"
                        "global_load_dword %13, %16, off offset:1664 sc0 sc1\n\t"
                        "global_load_dword %14, %16, off offset:1792 sc0 sc1\n\t"
                        "global_load_dword %15, %16, off offset:1920 sc0 sc1\n\t"
                        "s_waitcnt vmcnt(0)"
                        : "=&v"(v0),"=&v"(v1),"=&v"(v2),"=&v"(v3),
                          "=&v"(v4),"=&v"(v5),"=&v"(v6),"=&v"(v7),
                          "=&v"(v8),"=&v"(v9),"=&v"(v10),"=&v"(v11),
                          "=&v"(v12),"=&v"(v13),"=&v"(v14),"=&v"(v15)
                        : "v"(sb) : "memory");
                    bool ok = (v0 >= want) & (v1 >= want) & (v2 >= want) & (v3 >= want)
                            & (v4 >= want) & (v5 >= want) & (v6 >= want) & (v7 >= want)
                            & (v8 >= want) & (v9 >= want) & (v10 >= want) & (v11 >= want)
                            & (v12 >= want) & (v13 >= want) & (v14 >= want) & (v15 >= want);
                    if (ok) break;
                    if (++guard > (1L << 22)) break;   // fail visibly, not hang
                }
            }
            __builtin_amdgcn_s_barrier();   // B: group certified (sentinels seen)
            __builtin_amdgcn_sched_barrier(0);

            // ---- 9. x(t+2) prefetch: hidden under the bulk-load RT ----
            {
                int tn = (t + 2 < T_STEPS) ? (t + 2) : (T_STEPS - 1);
                const float* px = x + ((size_t)tn * BATCH + bb + row) * IN_D + seg * 8;
                px0 = *(const float4*)(px); px1 = *(const float4*)(px + 4);
            }

            // ---- 10. bulk load ONCE + embedded-tag verify (retry rare) ----
            {
                const unsigned char* pb = ex_rd + so;
                int4v e0, e1, e2, e3;
                long guard = 0;
                for (;;) {
                    asm volatile(
                        "global_load_dwordx4 %0, %4, off sc0 sc1\n\t"
                        "global_load_dwordx4 %1, %4, off offset:16 sc0 sc1\n\t"
                        "global_load_dwordx4 %2, %4, off offset:32 sc0 sc1\n\t"
                        "global_load_dwordx4 %3, %4, off offset:48 sc0 sc1\n\t"
                        "s_waitcnt vmcnt(0)"
                        : "=&v"(e0), "=&v"(e1), "=&v"(e2), "=&v"(e3)
                        : "v"(pb) : "memory");
                    if (((unsigned int)e0[2] == want) & ((unsigned int)e1[2] == want) &
                        ((unsigned int)e2[2] == want) & ((unsigned int)e3[2] == want)) break;
                    if (++guard > (1L << 22)) break;   // fail visibly, not hang
                }
                int f0 = (seg >> 1) * 64 + (seg & 1) * 32 + row;
                *(int4v*)(hfrag + FRAG_ADDR(f0))      = (int4v){e0[0], e0[1], e1[0], e1[1]};
                *(int4v*)(hfrag + FRAG_ADDR(f0 + 16)) = (int4v){e2[0], e2[1], e3[0], e3[1]};
            }

            // ---- 11. h_seq store (plain cached, off critical path) ----
            out[((size_t)t * BATCH + bb + row) * HID + hbase + seg] = hv;

            lds_barrier();   // C: hfrag/xfrag ready for next iteration
        } else {
            out[((size_t)t * BATCH + bb + row) * HID + hbase + seg] = hv;
            out_h[(size_t)(bb + row) * HID + hbase + seg] = hv;
            out_c[(size_t)(bb + row) * HID + hbase + seg] = c_reg;
        }
    };

    for (int t = 0; t < T_STEPS; t += 2) {
        STEP(t,     xa0, xa1, xb0, xb1);
        STEP(t + 1, xb0, xb1, xa0, xa1);
    }
}

extern "C" void kernel_launch(void* const* d_in, const int* in_sizes, int n_in,
                              void* d_out, int out_size, void* d_ws, size_t ws_size,
                              hipStream_t stream) {
    (void)in_sizes; (void)n_in; (void)out_size; (void)ws_size;
    const float* x   = (const float*)d_in[0];
    const float* h0  = (const float*)d_in[1];
    const float* c0  = (const float*)d_in[2];
    const float* Wf  = (const float*)d_in[3];
    const float* Wfb = (const float*)d_in[4];
    const float* Uf  = (const float*)d_in[5];
    const float* Ufb = (const float*)d_in[6];
    const float* Wi  = (const float*)d_in[7];
    const float* Wib = (const float*)d_in[8];
    const float* Ui  = (const float*)d_in[9];
    const float* Uib = (const float*)d_in[10];
    const float* Wo  = (const float*)d_in[11];
    const float* Wob = (const float*)d_in[12];
    const float* Uo  = (const float*)d_in[13];
    const float* Uob = (const float*)d_in[14];
    const float* Wc  = (const float*)d_in[15];
    const float* Wcb = (const float*)d_in[16];
    const float* Uc  = (const float*)d_in[17];
    const float* Ucb = (const float*)d_in[18];

    unsigned char* exch = (unsigned char*)d_ws;
    // zero both slots (packet tags must start < 1)
    const int nzero = 2 * SLOT_BYTES / 4;
    lstm_init_ws<<<(nzero + 255) / 256, 256, 0, stream>>>((unsigned int*)exch, nzero);
    lstm_persist<<<NGROUP * NSLICE, THREADS, 0, stream>>>(
        x, h0, c0,
        Wf, Wfb, Uf, Ufb, Wi, Wib, Ui, Uib,
        Wo, Wob, Uo, Uob, Wc, Wcb, Uc, Ucb,
        (float*)d_out, exch);
}